// Round 6
// baseline (747.014 us; speedup 1.0000x reference)
//
#include <hip/hip_runtime.h>
#include <math.h>

#define N_NODES 512
#define QLEN    1024
#define DIM     256
#define TJ      16             // context rows per tile
#define LROW    264            // padded LDS row stride; 264%32==8 -> 2-way aliasing (free)
#define HROWS   512            // context rows per half-block
#define NT      (HROWS / TJ)   // 32 tiles per block

#define AS1 __attribute__((address_space(1)))
#define AS3 __attribute__((address_space(3)))
#define GLD16(gsrc, ldst) \
  __builtin_amdgcn_global_load_lds((AS1 const void*)(gsrc), (AS3 void*)(ldst), 16, 0, 0)

// ---------------------------------------------------------------------------
// K1: 2 blocks per node (h=0,1), each streams HROWS=512 context rows.
// Per block: q = query@W_in^T (redundant, L2-cheap); per-wave online softmax
// over its private 4-row stripes; per-wave partials (m,l,A[256],B[256]) -> ws.
// Raw scores -> scores_out (normalized by K2). No in-loop barriers.
// LDS = 37.9 KB -> 4 blocks/CU; grid 1024 -> 16 waves/CU resident.
// ---------------------------------------------------------------------------
__global__ __launch_bounds__(256, 4) void rpps_half_kernel(
    const float* __restrict__ query,    // [N,1,D]
    const float* __restrict__ context,  // [N,Q,D]
    const float* __restrict__ W_in,     // [D,D]
    const float* __restrict__ ab,       // [N]
    float* __restrict__ scores_raw,     // [N,Q] raw scores
    float* __restrict__ Wm,             // [N*8] per-wave max
    float* __restrict__ Wl,             // [N*8] per-wave denom
    float* __restrict__ WA,             // [N*8][D]
    float* __restrict__ WB,             // [N*8][D]
    float* __restrict__ Wq)             // [N][D] projected q
{
  __shared__ float qs[DIM];
  __shared__ float qv[DIM];
  __shared__ float sc[HROWS];           // raw scores for this half
  __shared__ float tile[2][TJ * LROW];  // double-buffered context tile

  const int bid  = blockIdx.x;
  const int b    = bid >> 1;         // node
  const int h    = bid & 1;          // which half of the context
  const int tid  = threadIdx.x;
  const int wave = tid >> 6;
  const int lane = tid & 63;
  const int wg   = (tid >> 4) & 3;   // group within wave
  const int gl   = tid & 15;         // lane within 16-lane dot group
  const int row  = 4 * wave + wg;    // tile row this group owns

  const float* ctx = context + ((size_t)b * QLEN + (size_t)h * HROWS) * DIM;

  qs[tid] = query[b * DIM + tid];

  // prefetch tile 0 into buffer 0 (each wave stages exactly its own 4 rows)
  #pragma unroll
  for (int i = 0; i < 4; ++i)
    GLD16(ctx + (size_t)(4 * wave + i) * DIM + lane * 4,
          &tile[0][(4 * wave + i) * LROW]);

  // lgkm-only barrier: qs visible; prefetch stays in flight
  asm volatile("s_waitcnt lgkmcnt(0)\n\ts_barrier" ::: "memory");

  // q projection: qp = W_in[tid,:] . qs
  float qp = 0.f;
  {
    const float4* w4 = (const float4*)(W_in + (size_t)tid * DIM);
    #pragma unroll 8
    for (int k = 0; k < DIM / 4; ++k) {
      const float4 wv = w4[k];
      qp += wv.x * qs[4 * k] + wv.y * qs[4 * k + 1] +
            wv.z * qs[4 * k + 2] + wv.w * qs[4 * k + 3];
    }
  }
  qv[tid] = qp;
  asm volatile("s_waitcnt lgkmcnt(0)\n\ts_barrier" ::: "memory");

  float qreg[16];
  #pragma unroll
  for (int k = 0; k < 16; ++k) qreg[k] = qv[gl + 16 * k];   // my dims, in regs

  const float ab_v = ab[b];
  float m_w = -INFINITY, l_w = 0.f;
  float accA[16], accB[16];
  #pragma unroll
  for (int k = 0; k < 16; ++k) { accA[k] = 0.f; accB[k] = 0.f; }

  for (int t = 0; t < NT; ++t) {
    const int cur = t & 1;

    // guard: my ds_reads of buffer cur^1 (iteration t-1) have completed,
    // so the GLD16 rewrite of that buffer below cannot race them.
    asm volatile("s_waitcnt lgkmcnt(0)" ::: "memory");

    if (t + 1 < NT) {
      // issue prefetch of tile t+1 into the other buffer (wave-private rows)
      const float* src = ctx + (size_t)(t + 1) * TJ * DIM;
      float* dst = &tile[cur ^ 1][0];
      #pragma unroll
      for (int i = 0; i < 4; ++i)
        GLD16(src + (size_t)(4 * wave + i) * DIM + lane * 4,
              dst + (4 * wave + i) * LROW);
      // outstanding: 4 (tile t) + 4 just issued -> complete tile t only
      asm volatile("s_waitcnt vmcnt(4)" ::: "memory");
    } else {
      asm volatile("s_waitcnt vmcnt(0)" ::: "memory");
    }

    // read my 16 elems of row `row` (dims gl+16k) into registers
    const float* trow = &tile[cur][row * LROW + gl];
    float c[16];
    #pragma unroll
    for (int k = 0; k < 16; ++k) c[k] = trow[16 * k];

    // score: 16-lane group dot
    float s = 0.f;
    #pragma unroll
    for (int k = 0; k < 16; ++k) s += c[k] * qreg[k];
    s += __shfl_xor(s, 1);
    s += __shfl_xor(s, 2);
    s += __shfl_xor(s, 4);
    s += __shfl_xor(s, 8);

    if (gl == 0) sc[t * TJ + row] = s;   // raw score (LDS, lgkm-counted)

    // wave-local tile max over the 4 groups
    float tm = fmaxf(s, __shfl_xor(s, 16));
    tm = fmaxf(tm, __shfl_xor(tm, 32));

    if (tm > m_w) {                       // exact skip: rsc==1 otherwise
      const float rsc = __expf(m_w - tm); // exp(-inf)=0 on first tile
      m_w = tm;
      l_w *= rsc;
      #pragma unroll
      for (int k = 0; k < 16; ++k) { accA[k] *= rsc; accB[k] *= rsc; }
    }

    const float w  = __expf(s - m_w);
    const float bt = __expf(-ab_v * (float)(QLEN - 1 - (h * HROWS + t * TJ + row)));
    const float wb = w * bt;
    l_w += w;
    #pragma unroll
    for (int k = 0; k < 16; ++k) {
      accA[k] += w * c[k];
      accB[k] += wb * fabsf(c[k]);
    }
  }

  // ---- intra-wave reduce over the 4 groups (same wave-local m) ----
  #pragma unroll
  for (int k = 0; k < 16; ++k) {
    accA[k] += __shfl_xor(accA[k], 16);
    accA[k] += __shfl_xor(accA[k], 32);
    accB[k] += __shfl_xor(accB[k], 16);
    accB[k] += __shfl_xor(accB[k], 32);
  }
  l_w += __shfl_xor(l_w, 16);
  l_w += __shfl_xor(l_w, 32);

  // ---- write per-wave partials to workspace ----
  const int widx = ((b * 2 + h) << 2) + wave;          // [N][2][4]
  if (lane == 0) { Wm[widx] = m_w; Wl[widx] = l_w; }
  if (wg == 0) {
    #pragma unroll
    for (int k = 0; k < 16; ++k) {
      WA[(size_t)widx * DIM + gl + 16 * k] = accA[k];
      WB[(size_t)widx * DIM + gl + 16 * k] = accB[k];
    }
  }
  if (h == 0) Wq[b * DIM + tid] = qp;

  __syncthreads();   // all sc writes visible
  #pragma unroll
  for (int c2 = 0; c2 < 2; ++c2) {
    const int j = c2 * 256 + tid;
    scores_raw[(size_t)b * QLEN + h * HROWS + j] = sc[j];
  }
}

// ---------------------------------------------------------------------------
// K2: merge 8 per-wave partials per node; out = tanh([mix2;q]@W_out^T);
// normalize raw scores in place. 512 blocks x 256 threads, all L2-resident.
// ---------------------------------------------------------------------------
__global__ __launch_bounds__(256) void rpps_merge_kernel(
    const float* __restrict__ W_out,    // [D,2D]
    const float* __restrict__ ae,
    const float* __restrict__ ad,
    const float* __restrict__ Wm,
    const float* __restrict__ Wl,
    const float* __restrict__ WA,
    const float* __restrict__ WB,
    const float* __restrict__ Wq,
    float* __restrict__ out,            // [N,D]
    float* __restrict__ scores)         // [N,Q] raw -> normalized
{
  __shared__ float comb[2 * DIM];
  const int b = blockIdx.x, tid = threadIdx.x;

  float mv[8];
  #pragma unroll
  for (int w = 0; w < 8; ++w) mv[w] = Wm[b * 8 + w];
  float M = mv[0];
  #pragma unroll
  for (int w = 1; w < 8; ++w) M = fmaxf(M, mv[w]);

  float L = 0.f, A = 0.f, B = 0.f;
  #pragma unroll
  for (int w = 0; w < 8; ++w) {
    const float e = __expf(mv[w] - M);
    L += e * Wl[b * 8 + w];
    A += e * WA[(size_t)(b * 8 + w) * DIM + tid];
    B += e * WB[(size_t)(b * 8 + w) * DIM + tid];
  }
  const float invL = 1.f / L;
  const float cb   = fabsf(ae[b]) - fabsf(ad[b]);

  comb[tid]       = tanhf((A + cb * B) * invL);   // mix2
  comb[DIM + tid] = Wq[b * DIM + tid];            // projected q
  __syncthreads();

  float oacc = 0.f;
  {
    const float4* wo4 = (const float4*)(W_out + (size_t)tid * 2 * DIM);
    #pragma unroll 8
    for (int k = 0; k < (2 * DIM) / 4; ++k) {
      const float4 wv = wo4[k];
      oacc += wv.x * comb[4 * k] + wv.y * comb[4 * k + 1] +
              wv.z * comb[4 * k + 2] + wv.w * comb[4 * k + 3];
    }
  }
  out[(size_t)b * DIM + tid] = tanhf(oacc);

  // normalize attention weights in place
  #pragma unroll
  for (int c2 = 0; c2 < 4; ++c2) {
    const int j = c2 * 256 + tid;
    const float s = scores[(size_t)b * QLEN + j];
    scores[(size_t)b * QLEN + j] = __expf(s - M) * invL;
  }
}

// ---------------------------------------------------------------------------
extern "C" void kernel_launch(void* const* d_in, const int* in_sizes, int n_in,
                              void* d_out, int out_size, void* d_ws, size_t ws_size,
                              hipStream_t stream) {
  const float* query   = (const float*)d_in[0];
  const float* context = (const float*)d_in[1];
  const float* W_in    = (const float*)d_in[2];
  const float* W_out   = (const float*)d_in[3];
  const float* ae      = (const float*)d_in[4];
  const float* ad      = (const float*)d_in[5];
  const float* ab      = (const float*)d_in[6];
  // d_in[7] = index (unused)

  float* out        = (float*)d_out;                   // [N,1,D]
  float* scores_out = (float*)d_out + N_NODES * DIM;   // [N,1,Q]

  // workspace layout (floats), 16B-aligned sections
  float* Wm = (float*)d_ws;                 // [N*8]
  float* Wl = Wm + N_NODES * 8;             // [N*8]
  float* WA = Wl + N_NODES * 8;             // [N*8][D]
  float* WB = WA + (size_t)N_NODES * 8 * DIM;
  float* Wq = WB + (size_t)N_NODES * 8 * DIM;  // [N][D]

  hipLaunchKernelGGL(rpps_half_kernel, dim3(N_NODES * 2), dim3(256), 0, stream,
                     query, context, W_in, ab, scores_out, Wm, Wl, WA, WB, Wq);
  hipLaunchKernelGGL(rpps_merge_kernel, dim3(N_NODES), dim3(256), 0, stream,
                     W_out, ae, ad, Wm, Wl, WA, WB, Wq, out, scores_out);
}

// Round 7
// 724.774 us; speedup vs baseline: 1.0307x; 1.0307x over previous
//
#include <hip/hip_runtime.h>
#include <math.h>

#define N_NODES 512
#define QLEN    1024
#define DIM     256
#define TJ      16             // context rows per tile
#define LROW    264            // padded LDS row stride; 264%32==8 -> 2-way aliasing (free)
#define NT      (QLEN / TJ)    // 64 tiles
#define NBUF    3              // triple buffer, prefetch depth 2

#define AS1 __attribute__((address_space(1)))
#define AS3 __attribute__((address_space(3)))
#define GLD16(gsrc, ldst) \
  __builtin_amdgcn_global_load_lds((AS1 const void*)(gsrc), (AS3 void*)(ldst), 16, 0, 0)

// One block per node, 256 threads (4 waves). Fully fused:
//   q = query@W_in^T ; scores = q.ctx ; softmax ; A=sum w*c, B=sum w*bt*|c| ;
//   mix2 = tanh((A + (|ae|-|ad|)*B)/L) ; out = tanh([mix2;q]@W_out^T) ; attn weights.
// Wave-private tile stripes: wave w stages AND reads rows 4w..4w+3 only ->
// no in-loop barriers. Per-wave online softmax, flash-style merge at the end.
// Best-measured variant (R4: 724.8 us end-to-end incl. ~630 us harness floor).
__global__ __launch_bounds__(256, 2) void rpps_fused_kernel(
    const float* __restrict__ query,    // [N,1,D]
    const float* __restrict__ context,  // [N,Q,D]
    const float* __restrict__ W_in,     // [D,D]
    const float* __restrict__ W_out,    // [D,2D]
    const float* __restrict__ ae,
    const float* __restrict__ ad,
    const float* __restrict__ ab,
    float* __restrict__ out,            // [N,D]
    float* __restrict__ scores_out)     // [N,Q]
{
  __shared__ float qs[DIM];
  __shared__ float qv[DIM];
  __shared__ float sc[QLEN];                // raw scores for this node
  __shared__ float comb[2 * DIM];           // [mix2 ; q]
  __shared__ float redM[4], redL[4];        // per-wave merge state
  __shared__ float redA[4][DIM], redB[4][DIM];
  __shared__ float tile[NBUF][TJ * LROW];   // triple-buffered context tile

  const int b    = blockIdx.x;
  const int tid  = threadIdx.x;
  const int wave = tid >> 6;
  const int lane = tid & 63;
  const int wg   = (tid >> 4) & 3;   // group within wave
  const int gl   = tid & 15;         // lane within 16-lane dot group
  const int row  = 4 * wave + wg;    // tile row this group owns

  const float* ctx = context + (size_t)b * QLEN * DIM;

  qs[tid] = query[b * DIM + tid];

  // depth-2 prefetch: tiles 0 and 1 (each wave stages exactly its own rows)
  #pragma unroll
  for (int i = 0; i < 4; ++i)
    GLD16(ctx + (size_t)(4 * wave + i) * DIM + lane * 4,
          &tile[0][(4 * wave + i) * LROW]);
  #pragma unroll
  for (int i = 0; i < 4; ++i)
    GLD16(ctx + (size_t)(TJ + 4 * wave + i) * DIM + lane * 4,
          &tile[1][(4 * wave + i) * LROW]);

  // lgkm-only barrier: qs visible, prefetch stays in flight
  asm volatile("s_waitcnt lgkmcnt(0)\n\ts_barrier" ::: "memory");

  // q projection: qp = W_in[tid,:] . qs
  float qp = 0.f;
  {
    const float4* w4 = (const float4*)(W_in + (size_t)tid * DIM);
    #pragma unroll 8
    for (int k = 0; k < DIM / 4; ++k) {
      const float4 wv = w4[k];
      qp += wv.x * qs[4 * k] + wv.y * qs[4 * k + 1] +
            wv.z * qs[4 * k + 2] + wv.w * qs[4 * k + 3];
    }
  }
  qv[tid] = qp;
  asm volatile("s_waitcnt lgkmcnt(0)\n\ts_barrier" ::: "memory");

  float qreg[16];
  #pragma unroll
  for (int k = 0; k < 16; ++k) qreg[k] = qv[gl + 16 * k];   // my dims, in regs

  const float ab_v = ab[b];
  float m_w = -INFINITY, l_w = 0.f;
  float accA[16], accB[16];
  #pragma unroll
  for (int k = 0; k < 16; ++k) { accA[k] = 0.f; accB[k] = 0.f; }

  int slot_c = 0, slot_p = 2;
  for (int t = 0; t < NT; ++t) {
    // my 4 rows of tile t are the 4 oldest of my <=8 outstanding loads
    if (t < NT - 1) asm volatile("s_waitcnt vmcnt(4)" ::: "memory");
    else            asm volatile("s_waitcnt vmcnt(0)" ::: "memory");

    // issue prefetch of tile t+2 (wave-private rows -> no barrier needed:
    // my last read of this slot was 2 iterations ago, in my program order)
    if (t + 2 < NT) {
      const float* src = ctx + (size_t)(t + 2) * TJ * DIM;
      float* dst = &tile[slot_p][0];
      #pragma unroll
      for (int i = 0; i < 4; ++i)
        GLD16(src + (size_t)(4 * wave + i) * DIM + lane * 4,
              dst + (4 * wave + i) * LROW);
    }

    // read my 16 elems of row `row` (dims gl+16k) into registers
    const float* trow = &tile[slot_c][row * LROW + gl];
    float c[16];
    #pragma unroll
    for (int k = 0; k < 16; ++k) c[k] = trow[16 * k];

    // score: 16-lane group dot
    float s = 0.f;
    #pragma unroll
    for (int k = 0; k < 16; ++k) s += c[k] * qreg[k];
    s += __shfl_xor(s, 1);
    s += __shfl_xor(s, 2);
    s += __shfl_xor(s, 4);
    s += __shfl_xor(s, 8);

    if (gl == 0) sc[t * TJ + row] = s;   // raw score, unique addr per (t,row)

    // wave-local tile max over the 4 groups
    float tm = fmaxf(s, __shfl_xor(s, 16));
    tm = fmaxf(tm, __shfl_xor(tm, 32));

    if (tm > m_w) {                       // exact skip: rsc==1 otherwise
      const float rsc = __expf(m_w - tm); // exp(-inf)=0 on first tile
      m_w = tm;
      l_w *= rsc;
      #pragma unroll
      for (int k = 0; k < 16; ++k) { accA[k] *= rsc; accB[k] *= rsc; }
    }

    const float w  = __expf(s - m_w);
    const float bt = __expf(-ab_v * (float)(QLEN - 1 - (t * TJ + row)));
    const float wb = w * bt;
    l_w += w;
    #pragma unroll
    for (int k = 0; k < 16; ++k) {
      accA[k] += w * c[k];
      accB[k] += wb * fabsf(c[k]);
    }

    if (++slot_c == NBUF) slot_c = 0;
    if (++slot_p == NBUF) slot_p = 0;
  }

  // ---- intra-wave reduce over the 4 groups (same wave-local m) ----
  #pragma unroll
  for (int k = 0; k < 16; ++k) {
    accA[k] += __shfl_xor(accA[k], 16);
    accA[k] += __shfl_xor(accA[k], 32);
    accB[k] += __shfl_xor(accB[k], 16);
    accB[k] += __shfl_xor(accB[k], 32);
  }
  l_w += __shfl_xor(l_w, 16);
  l_w += __shfl_xor(l_w, 32);

  if (lane == 0) { redM[wave] = m_w; redL[wave] = l_w; }
  if (wg == 0) {
    #pragma unroll
    for (int k = 0; k < 16; ++k) {
      redA[wave][gl + 16 * k] = accA[k];
      redB[wave][gl + 16 * k] = accB[k];
    }
  }
  __syncthreads();   // red* and all sc writes visible

  // ---- cross-wave flash merge ----
  const float M  = fmaxf(fmaxf(redM[0], redM[1]), fmaxf(redM[2], redM[3]));
  const float e0 = __expf(redM[0] - M), e1 = __expf(redM[1] - M);
  const float e2 = __expf(redM[2] - M), e3 = __expf(redM[3] - M);
  const float L  = e0 * redL[0] + e1 * redL[1] + e2 * redL[2] + e3 * redL[3];
  const float A  = e0 * redA[0][tid] + e1 * redA[1][tid] +
                   e2 * redA[2][tid] + e3 * redA[3][tid];
  const float B  = e0 * redB[0][tid] + e1 * redB[1][tid] +
                   e2 * redB[2][tid] + e3 * redB[3][tid];
  const float invL = 1.f / L;
  const float cb   = fabsf(ae[b]) - fabsf(ad[b]);

  comb[tid]       = tanhf((A + cb * B) * invL);   // mix2
  comb[DIM + tid] = qp;                           // projected q (register)

  // normalized attention weights (coalesced, 4 per thread)
  #pragma unroll
  for (int c2 = 0; c2 < 4; ++c2) {
    const int j = c2 * 256 + tid;
    scores_out[(size_t)b * QLEN + j] = __expf(sc[j] - M) * invL;
  }

  __syncthreads();   // comb visible

  // ---- out = tanh([mix2;q] @ W_out^T), W_out row tid from L2 ----
  float oacc = 0.f;
  {
    const float4* wo4 = (const float4*)(W_out + (size_t)tid * 2 * DIM);
    #pragma unroll 8
    for (int k = 0; k < (2 * DIM) / 4; ++k) {
      const float4 wv = wo4[k];
      oacc += wv.x * comb[4 * k] + wv.y * comb[4 * k + 1] +
              wv.z * comb[4 * k + 2] + wv.w * comb[4 * k + 3];
    }
  }
  out[(size_t)b * DIM + tid] = tanhf(oacc);
}

// ---------------------------------------------------------------------------
extern "C" void kernel_launch(void* const* d_in, const int* in_sizes, int n_in,
                              void* d_out, int out_size, void* d_ws, size_t ws_size,
                              hipStream_t stream) {
  const float* query   = (const float*)d_in[0];
  const float* context = (const float*)d_in[1];
  const float* W_in    = (const float*)d_in[2];
  const float* W_out   = (const float*)d_in[3];
  const float* ae      = (const float*)d_in[4];
  const float* ad      = (const float*)d_in[5];
  const float* ab      = (const float*)d_in[6];
  // d_in[7] = index (unused)

  float* out        = (float*)d_out;                   // [N,1,D]
  float* scores_out = (float*)d_out + N_NODES * DIM;   // [N,1,Q]

  hipLaunchKernelGGL(rpps_fused_kernel, dim3(N_NODES), dim3(256), 0, stream,
                     query, context, W_in, W_out, ae, ad, ab, out, scores_out);
}